// Round 4
// baseline (591.541 us; speedup 1.0000x reference)
//
#include <hip/hip_runtime.h>
#include <hip/hip_bf16.h>
#include <stdint.h>

#define HH   1024
#define FF   1024
#define NE   32
#define NK   4
#define CAP  256
#define BK   32
#define TN   192

typedef __bf16 bf16x8 __attribute__((ext_vector_type(8)));
typedef __bf16 bf16x4 __attribute__((ext_vector_type(4)));
typedef __bf16 bf16x2 __attribute__((ext_vector_type(2)));
typedef float  f32x4v __attribute__((ext_vector_type(4)));

// ---------------- workspace layout (bytes) ----------------
#define OFF_TOK 1024        // 32*256*4 = 32 KiB
#define OFF_WGT 33792       // 32 KiB
#define OFF_ES  66560       // 16 KiB (packed e<<16|pos per token,k)
#define OFF_RW  82944       // 16 KiB (routing weight per token,k)
#define OFF_T   131072      // 2 MiB  bf16 t
#define OFF_H   2228224     // 16 MiB bf16 h (mlp1 out)
#define OFF_H2  19005440    // 16 MiB bf16 h2 (mlp2 out)

__global__ void k_zero(int* __restrict__ cnt) {
    if (threadIdx.x < NE) cnt[threadIdx.x] = 0;
}

// ---------------- router: rmsnorm + gate + top4 + lists ----------------
__global__ __launch_bounds__(256) void k_router(
    const float* __restrict__ x, const float* __restrict__ nscale,
    const float* __restrict__ gw, const float* __restrict__ gb,
    __bf16* __restrict__ tbf, int* __restrict__ cnt,
    int* __restrict__ tok, float* __restrict__ wgt,
    int* __restrict__ res, float* __restrict__ rw)
{
    const int t = blockIdx.x, tid = threadIdx.x;
    __shared__ float tl[HH];
    __shared__ float red[4];
    __shared__ float logits[NE];

    float4 xv = ((const float4*)(x + (size_t)t * HH))[tid];
    float ss = xv.x * xv.x + xv.y * xv.y + xv.z * xv.z + xv.w * xv.w;
    #pragma unroll
    for (int o = 32; o; o >>= 1) ss += __shfl_xor(ss, o);
    if ((tid & 63) == 0) red[tid >> 6] = ss;
    __syncthreads();
    const float mean = (red[0] + red[1] + red[2] + red[3]) * (1.0f / HH);
    const float r = rsqrtf(mean + 1e-5f);
    float4 sc = ((const float4*)nscale)[tid];
    float4 tv;
    tv.x = xv.x * r * sc.x; tv.y = xv.y * r * sc.y;
    tv.z = xv.z * r * sc.z; tv.w = xv.w * r * sc.w;

    ((float4*)tl)[tid] = tv;
    bf16x4 pv = { (__bf16)tv.x, (__bf16)tv.y, (__bf16)tv.z, (__bf16)tv.w };
    *(bf16x4*)(tbf + (size_t)t * HH + tid * 4) = pv;
    __syncthreads();

    const int e = tid >> 3, q = tid & 7;
    const float4* gr = (const float4*)(gw + e * HH + q * 128);
    const float4* tr = (const float4*)(tl + q * 128);
    float s = 0.f;
    #pragma unroll 8
    for (int j = 0; j < 32; ++j) {
        float4 g = gr[j], v = tr[j];
        s += g.x * v.x + g.y * v.y + g.z * v.z + g.w * v.w;
    }
    s += __shfl_xor(s, 1); s += __shfl_xor(s, 2); s += __shfl_xor(s, 4);
    if (q == 0) logits[e] = s + gb[e];
    __syncthreads();

    if (tid == 0) {
        float v[NK]; int id[NK]; unsigned used = 0;
        for (int k = 0; k < NK; ++k) {
            float best = -1e30f; int bi = 0;
            for (int ee = 0; ee < NE; ++ee)
                if (!((used >> ee) & 1u) && logits[ee] > best) { best = logits[ee]; bi = ee; }
            used |= 1u << bi; v[k] = best; id[k] = bi;
        }
        float ex[NK], se = 0.f;
        for (int k = 0; k < NK; ++k) { ex[k] = __expf(v[k] - v[0]); se += ex[k]; }
        const float inv = 1.0f / se;
        for (int k = 0; k < NK; ++k) {
            const float wk = ex[k] * inv;
            int pos = atomicAdd(&cnt[id[k]], 1);
            if (pos < CAP) {
                tok[id[k] * CAP + pos] = t;
                wgt[id[k] * CAP + pos] = wk;
            }
            res[t * NK + k] = (id[k] << 16) | (pos & 0xffff);
            rw[t * NK + k] = wk;
        }
    }
}

// ---------------- mlp1: h = swiglu(t @ w1[e]^T + b1) * route_w ----------------
// Direct-A: wave w owns 16 w1-rows; A frag loaded straight from global
// (lane(mr,qd) = w1[row0+mr][ks*32+qd*8..+7]), cvt at use, NO LDS for A.
// B (tokens) staged in LDS double-buffer with XOR swizzle. 1 barrier/step.
__global__ __launch_bounds__(256, 4) void k_mlp1(
    const float* __restrict__ w1, const float* __restrict__ b1,
    const __bf16* __restrict__ tbf, const int* __restrict__ cnt,
    const int* __restrict__ tok, const float* __restrict__ wgt,
    __bf16* __restrict__ h)
{
    const int mtile = blockIdx.x;   // 32 tiles x 64 w1-rows
    const int e     = blockIdx.y;
    const int ntile = blockIdx.z;
    const int tid   = threadIdx.x;

    int Me = cnt[e]; Me = Me > CAP ? CAP : Me;
    const int n0 = ntile * TN;
    if (n0 >= Me) return;
    int MeL = Me - n0; MeL = MeL > TN ? TN : MeL;
    const int nreal = (MeL + 15) >> 4;

    __shared__ __bf16 Bl[2][TN * BK];
    __shared__ float  wgtL[TN];

    int myTok = 0;
    if (tid < TN) {
        const int sl = n0 + tid;
        float w = 0.f;
        if (sl < Me) { myTok = tok[e * CAP + sl]; w = wgt[e * CAP + sl]; }
        wgtL[tid] = w;
    }

    f32x4v acc[12];
    #pragma unroll
    for (int j = 0; j < 12; ++j)
        #pragma unroll
        for (int q = 0; q < 4; ++q) acc[j][q] = 0.f;

    const int lane = tid & 63, wv = tid >> 6;
    const int mr = lane & 15, qd = lane >> 4;
    const int foff = mr * BK + ((qd ^ ((mr >> 1) & 3)) << 3);
    const int rs   = (tid >> 1) & 3;
    // A: row = mtile*64 + wv*16 + mr, cols qd*8..qd*8+7 within each k-window
    const float* aptr = w1 + ((size_t)e * 2048 + (size_t)mtile * 64 + wv * 16 + mr) * HH + qd * 8;
    const __bf16* tbase = tbf + (size_t)myTok * HH;

    float4 pa0, pa1;
    uint4  pb0, pb1, pb2, pb3;
    pa0 = ((const float4*)aptr)[0];
    pa1 = ((const float4*)aptr)[1];
    if (tid < TN) {
        const uint4* bs = (const uint4*)tbase;
        pb0 = bs[0]; pb1 = bs[1]; pb2 = bs[2]; pb3 = bs[3];
    }

    for (int ks = 0; ks < 32; ++ks) {
        const int p = ks & 1;
        if (tid < TN) {
            *(uint4*)&Bl[p][tid * BK + ((0 ^ rs) << 3)] = pb0;
            *(uint4*)&Bl[p][tid * BK + ((1 ^ rs) << 3)] = pb1;
            *(uint4*)&Bl[p][tid * BK + ((2 ^ rs) << 3)] = pb2;
            *(uint4*)&Bl[p][tid * BK + ((3 ^ rs) << 3)] = pb3;
        }
        // convert current A to MFMA frag (before prefetch clobbers regs)
        bf16x8 af;
        af[0]=(__bf16)pa0.x; af[1]=(__bf16)pa0.y; af[2]=(__bf16)pa0.z; af[3]=(__bf16)pa0.w;
        af[4]=(__bf16)pa1.x; af[5]=(__bf16)pa1.y; af[6]=(__bf16)pa1.z; af[7]=(__bf16)pa1.w;
        if (ks < 31) {
            const float4* s2 = (const float4*)(aptr + (ks + 1) * BK);
            pa0 = s2[0]; pa1 = s2[1];
            if (tid < TN) {
                const uint4* bs = (const uint4*)(tbase + (ks + 1) * BK);
                pb0 = bs[0]; pb1 = bs[1]; pb2 = bs[2]; pb3 = bs[3];
            }
        }
        __syncthreads();
        #pragma unroll
        for (int j = 0; j < 12; ++j) {
            if (j < nreal) {
                bf16x8 bfr = *(const bf16x8*)&Bl[p][j * 16 * BK + foff];
                acc[j] = __builtin_amdgcn_mfma_f32_16x16x32_bf16(af, bfr, acc[j], 0, 0, 0);
            }
        }
    }

    const size_t hbase = (size_t)e * CAP + n0;
    const int rowb = mtile * 64 + wv * 16 + qd * 4;   // even
    const float4 bv = *(const float4*)(b1 + e * 2048 + rowb);
    #pragma unroll
    for (int j = 0; j < 12; ++j) {
        const int slot = j * 16 + mr;
        if (j < nreal && slot < MeL) {
            f32x4v v = acc[j];
            const float wt = wgtL[slot];
            float g0 = v[0] + bv.x, l0 = v[1] + bv.y;
            float g1 = v[2] + bv.z, l1 = v[3] + bv.w;
            g0 = fminf(g0, 7.f);
            g1 = fminf(g1, 7.f);
            l0 = fminf(fmaxf(l0, -7.f), 7.f);
            l1 = fminf(fmaxf(l1, -7.f), 7.f);
            const float h0 = g0 * (1.f / (1.f + __expf(-1.702f * g0))) * (l0 + 1.f) * wt;
            const float h1 = g1 * (1.f / (1.f + __expf(-1.702f * g1))) * (l1 + 1.f) * wt;
            bf16x2 hv = { (__bf16)h0, (__bf16)h1 };
            *(bf16x2*)(h + (hbase + slot) * FF + (rowb >> 1)) = hv;
        }
    }
}

// ---------------- mlp2: h2[e,slot,:] = h @ w2[e]^T (bf16 out, no atomics) ----------------
// Direct-A like mlp1; 32-row M-tiles, wave pair (rgrp) shares A rows (L2 absorbs),
// wave nh splits the 12 N-subtiles in halves. 1024 active blocks -> 4/CU.
__global__ __launch_bounds__(256, 4) void k_mlp2(
    const float* __restrict__ w2, const __bf16* __restrict__ h,
    const int* __restrict__ cnt, __bf16* __restrict__ h2)
{
    const int mtile = blockIdx.x;   // 32 tiles x 32 out-cols
    const int e     = blockIdx.y;
    const int ntile = blockIdx.z;
    const int tid   = threadIdx.x;

    int Me = cnt[e]; Me = Me > CAP ? CAP : Me;
    const int n0 = ntile * TN;
    if (n0 >= Me) return;
    int MeL = Me - n0; MeL = MeL > TN ? TN : MeL;
    const int nreal = (MeL + 15) >> 4;

    __shared__ __bf16 Bl[2][TN * BK];

    const bool bval = (tid < TN) && (n0 + tid < CAP);
    const __bf16* hrow = h + ((size_t)e * CAP + n0 + tid) * FF;

    f32x4v acc[6];
    #pragma unroll
    for (int j = 0; j < 6; ++j)
        #pragma unroll
        for (int q = 0; q < 4; ++q) acc[j][q] = 0.f;

    const int lane = tid & 63, wv = tid >> 6;
    const int rgrp = wv >> 1, nh = wv & 1;
    const int mr = lane & 15, qd = lane >> 4;
    const int foff = mr * BK + ((qd ^ ((mr >> 1) & 3)) << 3);
    const int rs   = (tid >> 1) & 3;
    const float* aptr = w2 + ((size_t)e * HH + (size_t)mtile * 32 + rgrp * 16 + mr) * FF + qd * 8;

    float4 pa0, pa1;
    uint4  pb0 = {0,0,0,0}, pb1 = {0,0,0,0}, pb2 = {0,0,0,0}, pb3 = {0,0,0,0};
    pa0 = ((const float4*)aptr)[0];
    pa1 = ((const float4*)aptr)[1];
    if (bval) {
        const uint4* bs = (const uint4*)hrow;
        pb0 = bs[0]; pb1 = bs[1]; pb2 = bs[2]; pb3 = bs[3];
    }

    for (int ks = 0; ks < 32; ++ks) {
        const int p = ks & 1;
        if (tid < TN) {
            *(uint4*)&Bl[p][tid * BK + ((0 ^ rs) << 3)] = pb0;
            *(uint4*)&Bl[p][tid * BK + ((1 ^ rs) << 3)] = pb1;
            *(uint4*)&Bl[p][tid * BK + ((2 ^ rs) << 3)] = pb2;
            *(uint4*)&Bl[p][tid * BK + ((3 ^ rs) << 3)] = pb3;
        }
        bf16x8 af;
        af[0]=(__bf16)pa0.x; af[1]=(__bf16)pa0.y; af[2]=(__bf16)pa0.z; af[3]=(__bf16)pa0.w;
        af[4]=(__bf16)pa1.x; af[5]=(__bf16)pa1.y; af[6]=(__bf16)pa1.z; af[7]=(__bf16)pa1.w;
        if (ks < 31) {
            const float4* s2 = (const float4*)(aptr + (ks + 1) * BK);
            pa0 = s2[0]; pa1 = s2[1];
            if (bval) {
                const uint4* bs = (const uint4*)(hrow + (ks + 1) * BK);
                pb0 = bs[0]; pb1 = bs[1]; pb2 = bs[2]; pb3 = bs[3];
            }
        }
        __syncthreads();
        #pragma unroll
        for (int j = 0; j < 6; ++j) {
            const int nsub = nh * 6 + j;
            if (nsub < nreal) {
                bf16x8 bfr = *(const bf16x8*)&Bl[p][nsub * 16 * BK + foff];
                acc[j] = __builtin_amdgcn_mfma_f32_16x16x32_bf16(af, bfr, acc[j], 0, 0, 0);
            }
        }
    }

    const int colb = mtile * 32 + rgrp * 16 + qd * 4;
    #pragma unroll
    for (int j = 0; j < 6; ++j) {
        const int nsub = nh * 6 + j;
        const int slot = nsub * 16 + mr;
        if (nsub < nreal && slot < MeL) {
            f32x4v v = acc[j];
            bf16x4 ov = { (__bf16)v[0], (__bf16)v[1], (__bf16)v[2], (__bf16)v[3] };
            *(bf16x4*)&h2[((size_t)e * CAP + n0 + slot) * HH + colb] = ov;
        }
    }
}

// ---------------- combine: out = x + sum_k (h2[e_k,pos_k,:] + w_k*b2[e_k,:]) ----------------
__global__ __launch_bounds__(256) void k_combine(
    const float* __restrict__ x, const float* __restrict__ b2,
    const __bf16* __restrict__ h2, const int* __restrict__ res,
    const float* __restrict__ rw, float* __restrict__ out)
{
    const int t = blockIdx.x, tid = threadIdx.x;
    float4 acc = ((const float4*)(x + (size_t)t * HH))[tid];
    #pragma unroll
    for (int k = 0; k < NK; ++k) {
        const int es = res[t * NK + k];
        const float wt = rw[t * NK + k];
        const int e = es >> 16, pos = es & 0xffff;
        if (pos < CAP) {
            bf16x4 hv = *(const bf16x4*)(h2 + ((size_t)e * CAP + pos) * HH + tid * 4);
            float4 bv = ((const float4*)(b2 + (size_t)e * HH))[tid];
            acc.x += (float)hv[0] + wt * bv.x;
            acc.y += (float)hv[1] + wt * bv.y;
            acc.z += (float)hv[2] + wt * bv.z;
            acc.w += (float)hv[3] + wt * bv.w;
        }
    }
    ((float4*)(out + (size_t)t * HH))[tid] = acc;
}

extern "C" void kernel_launch(void* const* d_in, const int* in_sizes, int n_in,
                              void* d_out, int out_size, void* d_ws, size_t ws_size,
                              hipStream_t stream) {
    const float* x      = (const float*)d_in[0];
    const float* nscale = (const float*)d_in[1];
    const float* gw     = (const float*)d_in[2];
    const float* gb     = (const float*)d_in[3];
    const float* w1     = (const float*)d_in[4];
    const float* b1     = (const float*)d_in[5];
    const float* w2     = (const float*)d_in[6];
    const float* b2     = (const float*)d_in[7];
    float* out = (float*)d_out;

    char* ws = (char*)d_ws;
    int*    cnt = (int*)(ws);
    int*    tok = (int*)(ws + OFF_TOK);
    float*  wgt = (float*)(ws + OFF_WGT);
    int*    res = (int*)(ws + OFF_ES);
    float*  rw  = (float*)(ws + OFF_RW);
    __bf16* tbf = (__bf16*)(ws + OFF_T);
    __bf16* h   = (__bf16*)(ws + OFF_H);
    __bf16* h2  = (__bf16*)(ws + OFF_H2);

    k_zero<<<1, 64, 0, stream>>>(cnt);
    k_router<<<1024, 256, 0, stream>>>(x, nscale, gw, gb, tbf, cnt, tok, wgt, res, rw);
    k_mlp1<<<dim3(32, 32, 2), 256, 0, stream>>>(w1, b1, tbf, cnt, tok, wgt, h);
    k_mlp2<<<dim3(32, 32, 2), 256, 0, stream>>>(w2, h, cnt, h2);
    k_combine<<<1024, 256, 0, stream>>>(x, b2, h2, res, rw, out);
}